// Round 5
// baseline (106.833 us; speedup 1.0000x reference)
//
#include <hip/hip_runtime.h>
#include <stdint.h>

// QuantLinear eval forward — v4b: barrier-free main kernel (NT-store compile fix).
// B=524288 rows, IN_DIM=16 (64B/row), OUT_DIM=32 (128B/row), 4 chunks of 4.
// Kernel 1 (qlin_prep, 1 block): builds 256 packed sign-mask words + 32 biases
// into d_ws. Kernel 2 (qlin_main): no __syncthreads, no block-wide LDS build.
// Per wave: 64 rows as 4 slabs of 16; rolling 2-deep input preload; per slab
// quantize -> wave-private LDS transpose (1 ds_write_b32 + 2 ds_read_b128,
// conflict-free, no barrier) -> integer dot/round -> 2 contiguous 1KB
// non-temporal wave stores. Math path identical to rounds 1-3 (absmax 0).

#if __has_builtin(__builtin_amdgcn_sdot4)
#define HAVE_SDOT4 1
#else
#define HAVE_SDOT4 0
#endif

typedef float f32x4 __attribute__((ext_vector_type(4)));   // native vector for NT store

__device__ __forceinline__ int dot7(uint32_t q, uint32_t m) {
#if HAVE_SDOT4
    // bytes of q in [0,15], bytes of m in {0,1}; acc init = 7 (for the +7 of r15)
    return __builtin_amdgcn_sdot4((int)q, (int)m, 7, false);
#else
    // m has 0xFF bytes; horizontal byte-sum via multiply (sums <= 60, no carry)
    return (int)(((q & m) * 0x01010101u) >> 24) + 7;
#endif
}

// round(y/15) for y in [0,60], given y7 = y+7: exact via magic multiply (no ties).
__device__ __forceinline__ int r15(int y7) {
    return (int)(((uint32_t)y7 * 274u) >> 12);
}

// ---------- prep: masks (256 words) + bias (32 floats) into ws ----------
__global__ void qlin_prep(const float* __restrict__ wgt,
                          const float* __restrict__ pmin,
                          uint32_t* __restrict__ ws)
{
    const int t = threadIdx.x;   // 256 threads
    const uint32_t MASKBYTE = HAVE_SDOT4 ? 1u : 0xFFu;
    {
        int o = t >> 3, k = t & 7, c = k & 3, isM = k >> 2;
        const float* wrow = wgt + o * 16 + c * 4;
        uint32_t m = 0;
#pragma unroll
        for (int j = 0; j < 4; ++j) {
            float v = wrow[j];
            bool sel = isM ? (v < 0.0f) : (v > 0.0f);
            if (sel) m |= MASKBYTE << (8 * j);
        }
        ws[o * 8 + isM * 4 + c] = m;   // [o][{P:c0..3, M:c0..3}]
    }
    if (t < 32) {
        const float* wrow = wgt + t * 16;
        int s = 0;
#pragma unroll
        for (int j = 0; j < 16; ++j) {
            float v = wrow[j];
            s += (v > 0.0f) ? 1 : 0;
            s -= (v < 0.0f) ? 1 : 0;
        }
        // bias[o] = InMin * sum_j sign(w[o,j]); small-int -> float is exact
        ((float*)ws)[256 + t] = __fmul_rn(pmin[0], (float)s);
    }
}

// ---------- main ----------
__global__ __launch_bounds__(256) void qlin_main(
    const float* __restrict__ in, const uint32_t* __restrict__ ws,
    const float* __restrict__ pmin, const float* __restrict__ pmax,
    float* __restrict__ out, int nrows)
{
    __shared__ __align__(16) uint32_t xpose[256];   // 64 words per wave, wave-private
    const int t = threadIdx.x;
    const int lane = t & 63;
    const int wv = t >> 6;
    const size_t R0 = ((size_t)blockIdx.x * 4 + wv) * 64;   // 64 rows per wave
    (void)nrows;  // grid covers rows exactly

    // rolling 2-deep input preload (1KB coalesced per wave-load)
    const float4* inp = (const float4*)in + R0 * 4 + lane;
    float4 fa = inp[0];
    float4 fb = inp[64];

    const int ogrp = lane & 7;      // 4-output group this lane owns
    const int rsel = lane >> 3;     // row-within-8 this lane owns
    uint32_t* xp = xpose + (wv << 6);

    // masks + bias via L2-broadcast global loads (written by qlin_prep)
    const uint4* mw = (const uint4*)ws;
    const uint4 MP0 = mw[(ogrp * 4 + 0) * 2], MM0 = mw[(ogrp * 4 + 0) * 2 + 1];
    const uint4 MP1 = mw[(ogrp * 4 + 1) * 2], MM1 = mw[(ogrp * 4 + 1) * 2 + 1];
    const uint4 MP2 = mw[(ogrp * 4 + 2) * 2], MM2 = mw[(ogrp * 4 + 2) * 2 + 1];
    const uint4 MP3 = mw[(ogrp * 4 + 3) * 2], MM3 = mw[(ogrp * 4 + 3) * 2 + 1];
    const float4 bias = ((const float4*)((const float*)ws + 256))[ogrp];

    const float InMin = pmin[0];
    const float scale = __fsub_rn(pmax[0], InMin);
    const bool unit = (scale == 1.0f);

#define QUANT(F, QW)                                                        \
    {                                                                       \
        float e[4] = { F.x, F.y, F.z, F.w };                                \
        uint32_t pk = 0;                                                    \
        _Pragma("unroll")                                                   \
        for (int j = 0; j < 4; ++j) {                                       \
            float d  = __fsub_rn(e[j], InMin);                              \
            float sd;                                                       \
            if (unit) sd = d; else sd = __fdiv_rn(d, scale);                \
            float v  = __fmul_rn(sd, 15.0f);                                \
            float rr = rintf(v);                                            \
            rr = fminf(fmaxf(rr, 0.0f), 15.0f);                             \
            pk |= ((uint32_t)(int)rr) << (8 * j);                           \
        }                                                                   \
        QW = pk;                                                            \
    }

#define ROWCOMP(q0, q1, q2, q3, dst)                                        \
        {                                                                   \
            int a0 = r15(dot7(q0, MP0.x)) - r15(dot7(q0, MM0.x))            \
                   + r15(dot7(q1, MP0.y)) - r15(dot7(q1, MM0.y))            \
                   + r15(dot7(q2, MP0.z)) - r15(dot7(q2, MM0.z))            \
                   + r15(dot7(q3, MP0.w)) - r15(dot7(q3, MM0.w));           \
            int a1 = r15(dot7(q0, MP1.x)) - r15(dot7(q0, MM1.x))            \
                   + r15(dot7(q1, MP1.y)) - r15(dot7(q1, MM1.y))            \
                   + r15(dot7(q2, MP1.z)) - r15(dot7(q2, MM1.z))            \
                   + r15(dot7(q3, MP1.w)) - r15(dot7(q3, MM1.w));           \
            int a2 = r15(dot7(q0, MP2.x)) - r15(dot7(q0, MM2.x))            \
                   + r15(dot7(q1, MP2.y)) - r15(dot7(q1, MM2.y))            \
                   + r15(dot7(q2, MP2.z)) - r15(dot7(q2, MM2.z))            \
                   + r15(dot7(q3, MP2.w)) - r15(dot7(q3, MM2.w));           \
            int a3 = r15(dot7(q0, MP3.x)) - r15(dot7(q0, MM3.x))            \
                   + r15(dot7(q1, MP3.y)) - r15(dot7(q1, MM3.y))            \
                   + r15(dot7(q2, MP3.z)) - r15(dot7(q2, MM3.z))            \
                   + r15(dot7(q3, MP3.w)) - r15(dot7(q3, MM3.w));           \
            f32x4 res;                                                      \
            res.x = __fadd_rn(__fmul_rn((float)a0, scale), bias.x);         \
            res.y = __fadd_rn(__fmul_rn((float)a1, scale), bias.y);         \
            res.z = __fadd_rn(__fmul_rn((float)a2, scale), bias.z);         \
            res.w = __fadd_rn(__fmul_rn((float)a3, scale), bias.w);         \
            __builtin_nontemporal_store(res, (f32x4*)(dst));                \
        }

    // Per slab: quantize -> wave-private LDS transpose -> compute -> NT store.
    // ds_write: lane l -> word l (stride-1, free). ds_read_b128: 8 addresses x
    // 8-lane broadcast, 16B apart -> all 32 banks, conflict-free. Same-wave
    // RAW/WAR ordering via lgkmcnt (compiler-inserted), no barrier required.
#define SLAB(F, K, PRELOAD)                                                 \
    {                                                                       \
        uint32_t qw;                                                        \
        QUANT(F, qw);                                                       \
        xp[lane] = qw;                                                      \
        PRELOAD                                                             \
        const uint4 qA = *(const uint4*)(xp + (rsel << 2));                 \
        const uint4 qB = *(const uint4*)(xp + 32 + (rsel << 2));            \
        float* p0 = out + (R0 + (size_t)(K) * 16 + rsel) * 32 + (ogrp << 2);\
        ROWCOMP(qA.x, qA.y, qA.z, qA.w, p0);                                \
        ROWCOMP(qB.x, qB.y, qB.z, qB.w, p0 + 256);                          \
    }

    SLAB(fa, 0, fa = inp[128];)   // preload slab2 while computing slab0
    SLAB(fb, 1, fb = inp[192];)   // preload slab3 while computing slab1
    SLAB(fa, 2, )
    SLAB(fb, 3, )

#undef SLAB
#undef ROWCOMP
#undef QUANT
}

extern "C" void kernel_launch(void* const* d_in, const int* in_sizes, int n_in,
                              void* d_out, int out_size, void* d_ws, size_t ws_size,
                              hipStream_t stream) {
    (void)n_in; (void)ws_size; (void)out_size;
    const float* in  = (const float*)d_in[0];
    const float* wgt = (const float*)d_in[1];
    const float* mn  = (const float*)d_in[2];
    const float* mx  = (const float*)d_in[3];
    float* out = (float*)d_out;
    uint32_t* ws = (uint32_t*)d_ws;
    const int nrows = in_sizes[0] / 16;        // 524288
    const int blocks = nrows / 256;            // 2048 blocks x 4 waves x 64 rows

    qlin_prep<<<1, 256, 0, stream>>>(wgt, mn, ws);
    qlin_main<<<blocks, 256, 0, stream>>>(in, ws, mn, mx, out, nrows);
}